// Round 14
// baseline (520.173 us; speedup 1.0000x reference)
//
#include <hip/hip_runtime.h>

// VanillaRNN for MI355X (gfx950), round 14: FUSED producer/consumer.
// B=256, T=512, D=128, H=256, O=128, fp32 in/out.
//
// One kernel, 256 WGs x 512 threads:
//  - WGs 0..15  : the serial scan (one 16-row stream each), identical to
//    round 13 (own-k-tile in regs, rotation swizzle, lgkm-only barrier),
//    plus a per-4-chunk flag wait (acquire, AGENT scope -> L2 inv).
//  - WGs 16..255: producers. Compute xW^T = W_hx . x^T + b chunk-major
//    ((stream,chunk) pairs p = c*16+s, WG b handles p = b-16, +240, ...),
//    write d_ws in scan C-fragment order, publish flags[p] with a release
//    store (AGENT scope -> L2 writeback). Producers never wait on
//    consumers; all 256 WGs are co-resident (4 WGs/CU thread cap) -> no
//    deadlock. Flags zeroed each launch via hipMemsetAsync.
// Fallback: round-13 two-kernel path if ws_size < 64MB + 4KB.

typedef _Float16 f16;
typedef _Float16 f16x2 __attribute__((ext_vector_type(2)));
typedef _Float16 f16x4 __attribute__((ext_vector_type(4)));
typedef _Float16 f16x8 __attribute__((ext_vector_type(8)));
typedef float f32x4 __attribute__((ext_vector_type(4)));

#define NB 256
#define NT 512
#define ND 128
#define NH 256
#define NO 128
#define R  16            // batch rows per stream
#define TCH 8            // timesteps per chunk
#define NCH (NT / TCH)   // 64 chunks
#define STEP_F16 4096    // f16 elements per (stream, step) xw block
#define NPROD 240        // producer WGs in fused kernel
#define NPAIR (16 * NCH) // 1024 (stream, chunk) pairs
#define WS_XW ((size_t)16 * NT * STEP_F16 * 2)   // 67,108,864 bytes
#define WS_FUSED (WS_XW + 4096)

__device__ __forceinline__ float fast_tanh(float z) {
  float e = __builtin_amdgcn_exp2f(z * 2.88539008177793f);
  float r = __builtin_amdgcn_rcpf(e + 1.0f);
  return __builtin_fmaf(-2.0f, r, 1.0f);
}

__device__ __forceinline__ f16x8 cvt8(const float* __restrict__ p) {
  f32x4 v0 = *(const f32x4*)p;
  f32x4 v1 = *(const f32x4*)(p + 4);
  f16x8 r;
  r[0] = (f16)v0.x; r[1] = (f16)v0.y; r[2] = (f16)v0.z; r[3] = (f16)v0.w;
  r[4] = (f16)v1.x; r[5] = (f16)v1.y; r[6] = (f16)v1.z; r[7] = (f16)v1.w;
  return r;
}

__device__ __forceinline__ f16x8 cvt44(const float* __restrict__ p0,
                                       const float* __restrict__ p1) {
  f32x4 a = *(const f32x4*)p0;
  f32x4 b = *(const f32x4*)p1;
  f16x8 r;
  r[0] = (f16)a.x; r[1] = (f16)a.y; r[2] = (f16)a.z; r[3] = (f16)a.w;
  r[4] = (f16)b.x; r[5] = (f16)b.y; r[6] = (f16)b.z; r[7] = (f16)b.w;
  return r;
}

// ===== scan step (round 13): own k-tile from regs, rotation swizzle =====
#define DO_STEP(CUR, ACIN, ACOUT, XWPF, XWIN, H8K, TAU)                     \
  {                                                                         \
    f16x8 bfr[7];                                                           \
    _Pragma("unroll")                                                       \
    for (int kr = 1; kr < 8; ++kr)                                          \
      bfr[kr - 1] = *(const f16x8*)((const char*)&hbuf[CUR][l15][0] +       \
                ((((w2 + kr) * 4 + g + l15) & 31) << 4));                   \
    int pf = (TAU) + 2; pf = pf < NT ? pf : NT - 1;                         \
    _Pragma("unroll")                                                       \
    for (int ct = 0; ct < 2; ++ct)                                          \
      XWPF[ct] = *(const f16x4*)(wsg + (size_t)pf * STEP_F16 + ct * 256);   \
    _Pragma("unroll")                                                       \
    for (int ct = 0; ct < 2; ++ct)                                          \
      ACIN[ct] = __builtin_amdgcn_mfma_f32_16x16x32_f16(fWh[ct][0], H8K,    \
                   ACIN[ct], 0, 0, 0);                                      \
    _Pragma("unroll")                                                       \
    for (int kr = 1; kr < 8; ++kr) {                                        \
      _Pragma("unroll")                                                     \
      for (int ct = 0; ct < 2; ++ct)                                        \
        ACIN[ct] = __builtin_amdgcn_mfma_f32_16x16x32_f16(fWh[ct][kr],      \
                     bfr[kr - 1], ACIN[ct], 0, 0, 0);                       \
    }                                                                       \
    {                                                                       \
      f16x8 h8;                                                             \
      _Pragma("unroll")                                                     \
      for (int ct = 0; ct < 2; ++ct)                                        \
        _Pragma("unroll")                                                   \
        for (int rg = 0; rg < 4; ++rg)                                      \
          h8[ct * 4 + rg] = (f16)fast_tanh(ACIN[ct][rg]);                   \
      *(f16x8*)((char*)&hbuf[(CUR) ^ 1][l15][0] +                           \
                (((w2 * 4 + g + l15) & 31) << 4)) = h8;                     \
      H8K = h8;                                                             \
    }                                                                       \
    _Pragma("unroll")                                                       \
    for (int ct = 0; ct < 2; ++ct) {                                        \
      ACOUT[ct][0] = (float)XWIN[ct][0]; ACOUT[ct][1] = (float)XWIN[ct][1]; \
      ACOUT[ct][2] = (float)XWIN[ct][2]; ACOUT[ct][3] = (float)XWIN[ct][3]; \
    }                                                                       \
    asm volatile("s_waitcnt lgkmcnt(0)\n\ts_barrier" ::: "memory");         \
    __builtin_amdgcn_sched_barrier(0);                                      \
  }

// ================= Fused kernel ====================
__global__ __launch_bounds__(512, 2)
void rnn_fused(const float* __restrict__ x,
               const float* __restrict__ Wx, const float* __restrict__ bx,
               const float* __restrict__ Wh, const float* __restrict__ bh,
               const float* __restrict__ Wp, const float* __restrict__ bp,
               f16* __restrict__ ws, unsigned* __restrict__ flags,
               float* __restrict__ out)
{
  __shared__ alignas(16) f16 smem[16384];   // 32 KB (producer), scan uses 16
  const int tid = threadIdx.x;
  const int w2  = tid >> 6;          // wave 0..7
  const int l15 = tid & 15;
  const int g   = (tid >> 4) & 3;

  if (blockIdx.x >= 16) {
    // ---------------- producer role ----------------
    f16 (*xlds)[ND] = (f16 (*)[ND])smem;

    f16x8 fWx[2][4];                 // 32-unit strip per wave
    f32x4 bias2[2];
    #pragma unroll
    for (int ct = 0; ct < 2; ++ct) {
      const int j = w2 * 32 + ct * 16 + l15;
      #pragma unroll
      for (int kt = 0; kt < 4; ++kt)
        fWx[ct][kt] = cvt8(Wx + (size_t)j * ND + kt * 32 + g * 8);
      const int j0 = w2 * 32 + ct * 16 + g * 4;
      #pragma unroll
      for (int rg = 0; rg < 4; ++rg)
        bias2[ct][rg] = bx[j0 + rg] + bh[j0 + rg];
    }

    #pragma unroll 1
    for (int p = blockIdx.x - 16; p < NPAIR; p += NPROD) {
      const int s = p & 15;          // stream
      const int c = p >> 4;          // chunk
      // stage x[s-rows, chunk] -> LDS f16, XOR-swizzled (coalesced f32x4)
      #pragma unroll
      for (int jj = 0; jj < 8; ++jj) {
        const int fi = (tid + jj * 512) * 4;   // flat float idx in chunk
        const int t  = fi >> 11;               // / (16 rows * 128 d)
        const int rr = (fi >> 7) & 15;
        const int d  = fi & 127;
        f32x4 v = *(const f32x4*)(x + ((size_t)(s * R + rr) * NT
                                     + (size_t)(c * TCH + t)) * ND + d);
        const int m = t * R + rr;
        f16x4 h4;
        h4[0] = (f16)v.x; h4[1] = (f16)v.y; h4[2] = (f16)v.z; h4[3] = (f16)v.w;
        *(f16x4*)((char*)&xlds[m][0] + ((2 * d) ^ ((m & 7) << 4))) = h4;
      }
      __syncthreads();

      #pragma unroll
      for (int t = 0; t < TCH; ++t) {
        f16x8 b[4];
        #pragma unroll
        for (int kt = 0; kt < 4; ++kt) {
          const int m = t * R + l15;
          b[kt] = *(const f16x8*)((char*)&xlds[m][0] +
                   ((kt * 64 + g * 16) ^ ((m & 7) << 4)));
        }
        f16* wsp = ws + ((size_t)(s * NT + c * TCH + t)) * STEP_F16
                      + (w2 * 2) * 256 + g * 64 + l15 * 4;
        #pragma unroll
        for (int ct = 0; ct < 2; ++ct) {
          f32x4 ac = bias2[ct];
          #pragma unroll
          for (int kt = 0; kt < 4; ++kt)
            ac = __builtin_amdgcn_mfma_f32_16x16x32_f16(fWx[ct][kt], b[kt], ac, 0, 0, 0);
          f16x4 pk;
          pk[0] = (f16)ac[0]; pk[1] = (f16)ac[1];
          pk[2] = (f16)ac[2]; pk[3] = (f16)ac[3];
          *(f16x4*)(wsp + ct * 256) = pk;
        }
      }
      // publish: all stores device-visible, then release flag
      __threadfence();
      __syncthreads();
      if (tid == 0)
        __hip_atomic_store(&flags[p], 1u, __ATOMIC_RELEASE,
                           __HIP_MEMORY_SCOPE_AGENT);
    }
    return;
  }

  // ---------------- scan role (round 13 + flag waits) ----------------
  const int wg = blockIdx.x;         // stream id 0..15
  f16 (*hbuf)[R][NH] = (f16 (*)[R][NH])smem;   // [2][16][256], 16 KB

  f16x8 fWh[2][8];                   // wave-rotated, permuted columns
  #pragma unroll
  for (int ct = 0; ct < 2; ++ct) {
    const int j = w2 * 32 + ct * 16 + l15;
    #pragma unroll
    for (int kr = 0; kr < 8; ++kr) {
      const int kta = (w2 + kr) & 7;
      fWh[ct][kr] = cvt44(Wh + (size_t)j * NH + kta * 32 + g * 4,
                          Wh + (size_t)j * NH + kta * 32 + 16 + g * 4);
    }
  }

  {
    unsigned* hz = (unsigned*)&hbuf[0][0][0];
    #pragma unroll
    for (int k = 0; k < (2 * R * NH / 2) / 512; ++k) hz[tid + k * 512] = 0u;
  }

  // wait for chunks 0..4 of this stream (reads during chunks 0..3 reach 4)
  if (tid < 5) {
    int cc = tid; if (cc > NCH - 1) cc = NCH - 1;
    const int fidx = cc * 16 + wg;
    while (__hip_atomic_load(&flags[fidx], __ATOMIC_ACQUIRE,
                             __HIP_MEMORY_SCOPE_AGENT) == 0u)
      __builtin_amdgcn_s_sleep(8);
  }
  __syncthreads();   // also makes h0 zeros visible

  const f16* wsg = ws + (size_t)wg * NT * STEP_F16
                 + (size_t)(w2 * 2) * 256 + g * 64 + l15 * 4;

  f16x4 xA[2], xB[2];
  #pragma unroll
  for (int ct = 0; ct < 2; ++ct) xA[ct] = *(const f16x4*)(wsg + 0 * STEP_F16 + ct * 256);
  #pragma unroll
  for (int ct = 0; ct < 2; ++ct) xB[ct] = *(const f16x4*)(wsg + 1 * STEP_F16 + ct * 256);

  f32x4 acA[2], acB[2];
  #pragma unroll
  for (int ct = 0; ct < 2; ++ct) {
    acA[ct][0] = (float)xA[ct][0]; acA[ct][1] = (float)xA[ct][1];
    acA[ct][2] = (float)xA[ct][2]; acA[ct][3] = (float)xA[ct][3];
  }

  f16x8 h8k;
  #pragma unroll
  for (int i = 0; i < 8; ++i) h8k[i] = (f16)0.f;

  #pragma unroll 1
  for (int c4 = 0; c4 < NCH; c4 += 4) {
    if (c4 > 0) {
      // ensure chunks c4+1 .. c4+4 ready (group reads reach chunk c4+4)
      if (tid < 4) {
        int cc = c4 + 1 + tid; if (cc > NCH - 1) cc = NCH - 1;
        const int fidx = cc * 16 + wg;
        while (__hip_atomic_load(&flags[fidx], __ATOMIC_ACQUIRE,
                                 __HIP_MEMORY_SCOPE_AGENT) == 0u)
          __builtin_amdgcn_s_sleep(8);
      }
      __syncthreads();
    }
    #pragma unroll 1
    for (int tau = c4 * 8; tau < c4 * 8 + 32; tau += 2) {
      DO_STEP(0, acA, acB, xA, xB, h8k, tau);
      DO_STEP(1, acB, acA, xB, xA, h8k, tau + 1);
    }
  }
  // final h is in hbuf[0]

  // ---- output projection: out^T = W_ph . h_T^T + b_ph ----
  f16x8 bh8[8];
  #pragma unroll
  for (int kt = 0; kt < 8; ++kt)
    bh8[kt] = *(const f16x8*)((const char*)&hbuf[0][l15][0] +
              (((kt * 4 + g + l15) & 31) << 4));
  {
    const int j0 = w2 * 16 + g * 4;
    f32x4 ac = {bp[j0], bp[j0 + 1], bp[j0 + 2], bp[j0 + 3]};
    #pragma unroll
    for (int kt = 0; kt < 8; ++kt) {
      const float* wrow = Wp + (size_t)(w2 * 16 + l15) * NH;
      f16x8 afr = cvt44(wrow + kt * 32 + g * 4, wrow + kt * 32 + 16 + g * 4);
      ac = __builtin_amdgcn_mfma_f32_16x16x32_f16(afr, bh8[kt], ac, 0, 0, 0);
    }
    #pragma unroll
    for (int rg = 0; rg < 4; ++rg)
      out[(size_t)(wg * R + l15) * NO + j0 + rg] = ac[rg];
  }
}

// ============ Fallback tier 2: round-13 two-kernel path ============
__global__ __launch_bounds__(256, 2)
void xw_gemm(const float* __restrict__ x,
             const float* __restrict__ Wx, const float* __restrict__ bx,
             const float* __restrict__ bh, f16* __restrict__ ws)
{
  const int wgb = blockIdx.x & 15;
  const int c   = blockIdx.x >> 4;
  const int tid = threadIdx.x;
  const int w   = tid >> 6;
  const int l15 = tid & 15;
  const int g   = (tid >> 4) & 3;

  __shared__ alignas(16) f16 xlds[TCH * R][ND];

  f16x8 fWx[4][4];
  f32x4 bias4[4];
  #pragma unroll
  for (int ct = 0; ct < 4; ++ct) {
    const int j = w * 64 + ct * 16 + l15;
    #pragma unroll
    for (int kt = 0; kt < 4; ++kt)
      fWx[ct][kt] = cvt8(Wx + (size_t)j * ND + kt * 32 + g * 8);
    const int j0 = w * 64 + ct * 16 + g * 4;
    #pragma unroll
    for (int rg = 0; rg < 4; ++rg)
      bias4[ct][rg] = bx[j0 + rg] + bh[j0 + rg];
  }

  const int srow = tid >> 4;
  const int sq   = tid & 15;
  const float* xc = x + ((size_t)(wgb * R + srow) * NT + (size_t)c * TCH) * ND;
  #pragma unroll
  for (int jj = 0; jj < 16; ++jj) {
    const int f = (sq + jj * 16) * 4;
    f32x4 v = *(const f32x4*)(xc + f);
    const int t = f >> 7;
    const int d = f & (ND - 1);
    const int m = t * R + srow;
    f16x4 h4;
    h4[0] = (f16)v.x; h4[1] = (f16)v.y; h4[2] = (f16)v.z; h4[3] = (f16)v.w;
    *(f16x4*)((char*)&xlds[m][0] + ((2 * d) ^ ((m & 7) << 4))) = h4;
  }
  __syncthreads();

  #pragma unroll
  for (int t = 0; t < TCH; ++t) {
    f16x8 b[4];
    #pragma unroll
    for (int kt = 0; kt < 4; ++kt) {
      const int m = t * R + l15;
      b[kt] = *(const f16x8*)((char*)&xlds[m][0] +
               ((kt * 64 + g * 16) ^ ((m & 7) << 4)));
    }
    f16* wsp = ws + ((size_t)(wgb * NT + c * TCH + t)) * STEP_F16
                  + w * 1024 + g * 64 + l15 * 4;
    #pragma unroll
    for (int ct = 0; ct < 4; ++ct) {
      f32x4 ac = bias4[ct];
      #pragma unroll
      for (int kt = 0; kt < 4; ++kt)
        ac = __builtin_amdgcn_mfma_f32_16x16x32_f16(fWx[ct][kt], b[kt], ac, 0, 0, 0);
      f16x4 p;
      p[0] = (f16)ac[0]; p[1] = (f16)ac[1]; p[2] = (f16)ac[2]; p[3] = (f16)ac[3];
      *(f16x4*)(wsp + ct * 256) = p;
    }
  }
}

__global__ __launch_bounds__(512, 2)
void rnn_scan(const f16* __restrict__ ws,
              const float* __restrict__ Wh,
              const float* __restrict__ Wp, const float* __restrict__ bp,
              float* __restrict__ out)
{
  const int wg  = blockIdx.x;
  const int tid = threadIdx.x;
  const int w2  = tid >> 6;
  const int l15 = tid & 15;
  const int g   = (tid >> 4) & 3;

  __shared__ alignas(16) f16 hbuf[2][R][NH];

  f16x8 fWh[2][8];
  #pragma unroll
  for (int ct = 0; ct < 2; ++ct) {
    const int j = w2 * 32 + ct * 16 + l15;
    #pragma unroll
    for (int kr = 0; kr < 8; ++kr) {
      const int kta = (w2 + kr) & 7;
      fWh[ct][kr] = cvt44(Wh + (size_t)j * NH + kta * 32 + g * 4,
                          Wh + (size_t)j * NH + kta * 32 + 16 + g * 4);
    }
  }

  {
    unsigned* hz = (unsigned*)&hbuf[0][0][0];
    #pragma unroll
    for (int k = 0; k < (2 * R * NH / 2) / 512; ++k) hz[tid + k * 512] = 0u;
  }

  const f16* wsg = ws + (size_t)wg * NT * STEP_F16
                 + (size_t)(w2 * 2) * 256 + g * 64 + l15 * 4;

  f16x4 xA[2], xB[2];
  #pragma unroll
  for (int ct = 0; ct < 2; ++ct) xA[ct] = *(const f16x4*)(wsg + 0 * STEP_F16 + ct * 256);
  #pragma unroll
  for (int ct = 0; ct < 2; ++ct) xB[ct] = *(const f16x4*)(wsg + 1 * STEP_F16 + ct * 256);

  f32x4 acA[2], acB[2];
  #pragma unroll
  for (int ct = 0; ct < 2; ++ct) {
    acA[ct][0] = (float)xA[ct][0]; acA[ct][1] = (float)xA[ct][1];
    acA[ct][2] = (float)xA[ct][2]; acA[ct][3] = (float)xA[ct][3];
  }

  f16x8 h8k;
  #pragma unroll
  for (int i = 0; i < 8; ++i) h8k[i] = (f16)0.f;

  __syncthreads();

  #pragma unroll 1
  for (int tau = 0; tau < NT; tau += 2) {
    DO_STEP(0, acA, acB, xA, xB, h8k, tau);
    DO_STEP(1, acB, acA, xB, xA, h8k, tau + 1);
  }

  f16x8 bh8[8];
  #pragma unroll
  for (int kt = 0; kt < 8; ++kt)
    bh8[kt] = *(const f16x8*)((const char*)&hbuf[0][l15][0] +
              (((kt * 4 + g + l15) & 31) << 4));
  {
    const int j0 = w2 * 16 + g * 4;
    f32x4 ac = {bp[j0], bp[j0 + 1], bp[j0 + 2], bp[j0 + 3]};
    #pragma unroll
    for (int kt = 0; kt < 8; ++kt) {
      const float* wrow = Wp + (size_t)(w2 * 16 + l15) * NH;
      f16x8 afr = cvt44(wrow + kt * 32 + g * 4, wrow + kt * 32 + 16 + g * 4);
      ac = __builtin_amdgcn_mfma_f32_16x16x32_f16(afr, bh8[kt], ac, 0, 0, 0);
    }
    #pragma unroll
    for (int rg = 0; rg < 4; ++rg)
      out[(size_t)(wg * R + l15) * NO + j0 + rg] = ac[rg];
  }
}

extern "C" void kernel_launch(void* const* d_in, const int* in_sizes, int n_in,
                              void* d_out, int out_size, void* d_ws, size_t ws_size,
                              hipStream_t stream) {
  const float* x   = (const float*)d_in[0];
  const float* whx = (const float*)d_in[1];
  const float* bhx = (const float*)d_in[2];
  const float* whh = (const float*)d_in[3];
  const float* bhh = (const float*)d_in[4];
  const float* wph = (const float*)d_in[5];
  const float* bph = (const float*)d_in[6];
  float* out = (float*)d_out;
  f16* ws = (f16*)d_ws;

  if (ws_size >= WS_FUSED) {
    unsigned* flags = (unsigned*)((char*)d_ws + WS_XW);
    hipMemsetAsync(flags, 0, 4096, stream);
    rnn_fused<<<dim3(16 + NPROD), dim3(512), 0, stream>>>(
        x, whx, bhx, whh, bhh, wph, bph, ws, flags, out);
  } else {
    xw_gemm<<<dim3(16 * NCH), dim3(256), 0, stream>>>(x, whx, bhx, bhh, ws);
    rnn_scan<<<dim3(16), dim3(512), 0, stream>>>(ws, whh, wph, bph, out);
  }
}

// Round 15
// 518.683 us; speedup vs baseline: 1.0029x; 1.0029x over previous
//
#include <hip/hip_runtime.h>

// VanillaRNN for MI355X (gfx950), round 15: fused producer/consumer with
// FORCED 1 WG/CU (96KB dynamic LDS). B=256,T=512,D=128,H=256,O=128, fp32.
//
// One kernel, 256 WGs x 512 threads, 96KB dynamic LDS -> exactly 1 WG/CU
// (round-14 lesson: at 32KB static LDS, 2 WGs/CU colocated and producers
// stole the scan's issue slots; scan slowed 1.8x).
//  - WGs 0..15  : round-13 serial scan (own-k-tile regs, rotation swizzle,
//    lgkm-only barrier) + per-4-chunk acquire flag waits.
//  - WGs 16..255: producers, chunk-major (p=c*16+s), release-publish flags.
// All 256 WGs co-resident (1/CU) -> scan CUs are dedicated; no deadlock.
// Fallback: round-13 two-kernel path if ws_size < 64MB+4KB.

typedef _Float16 f16;
typedef _Float16 f16x2 __attribute__((ext_vector_type(2)));
typedef _Float16 f16x4 __attribute__((ext_vector_type(4)));
typedef _Float16 f16x8 __attribute__((ext_vector_type(8)));
typedef float f32x4 __attribute__((ext_vector_type(4)));

#define NB 256
#define NT 512
#define ND 128
#define NH 256
#define NO 128
#define R  16            // batch rows per stream
#define TCH 8            // timesteps per chunk
#define NCH (NT / TCH)   // 64 chunks
#define STEP_F16 4096    // f16 elements per (stream, step) xw block
#define NPROD 240        // producer WGs in fused kernel
#define NPAIR (16 * NCH) // 1024 (stream, chunk) pairs
#define WS_XW ((size_t)16 * NT * STEP_F16 * 2)   // 67,108,864 bytes
#define WS_FUSED (WS_XW + 4096)
#define DYN_LDS (96 * 1024)

__device__ __forceinline__ float fast_tanh(float z) {
  float e = __builtin_amdgcn_exp2f(z * 2.88539008177793f);
  float r = __builtin_amdgcn_rcpf(e + 1.0f);
  return __builtin_fmaf(-2.0f, r, 1.0f);
}

__device__ __forceinline__ f16x8 cvt8(const float* __restrict__ p) {
  f32x4 v0 = *(const f32x4*)p;
  f32x4 v1 = *(const f32x4*)(p + 4);
  f16x8 r;
  r[0] = (f16)v0.x; r[1] = (f16)v0.y; r[2] = (f16)v0.z; r[3] = (f16)v0.w;
  r[4] = (f16)v1.x; r[5] = (f16)v1.y; r[6] = (f16)v1.z; r[7] = (f16)v1.w;
  return r;
}

__device__ __forceinline__ f16x8 cvt44(const float* __restrict__ p0,
                                       const float* __restrict__ p1) {
  f32x4 a = *(const f32x4*)p0;
  f32x4 b = *(const f32x4*)p1;
  f16x8 r;
  r[0] = (f16)a.x; r[1] = (f16)a.y; r[2] = (f16)a.z; r[3] = (f16)a.w;
  r[4] = (f16)b.x; r[5] = (f16)b.y; r[6] = (f16)b.z; r[7] = (f16)b.w;
  return r;
}

// ===== scan step (round 13): own k-tile from regs, rotation swizzle =====
#define DO_STEP(CUR, ACIN, ACOUT, XWPF, XWIN, H8K, TAU)                     \
  {                                                                         \
    f16x8 bfr[7];                                                           \
    _Pragma("unroll")                                                       \
    for (int kr = 1; kr < 8; ++kr)                                          \
      bfr[kr - 1] = *(const f16x8*)((const char*)&hbuf[CUR][l15][0] +       \
                ((((w2 + kr) * 4 + g + l15) & 31) << 4));                   \
    int pf = (TAU) + 2; pf = pf < NT ? pf : NT - 1;                         \
    _Pragma("unroll")                                                       \
    for (int ct = 0; ct < 2; ++ct)                                          \
      XWPF[ct] = *(const f16x4*)(wsg + (size_t)pf * STEP_F16 + ct * 256);   \
    _Pragma("unroll")                                                       \
    for (int ct = 0; ct < 2; ++ct)                                          \
      ACIN[ct] = __builtin_amdgcn_mfma_f32_16x16x32_f16(fWh[ct][0], H8K,    \
                   ACIN[ct], 0, 0, 0);                                      \
    _Pragma("unroll")                                                       \
    for (int kr = 1; kr < 8; ++kr) {                                        \
      _Pragma("unroll")                                                     \
      for (int ct = 0; ct < 2; ++ct)                                        \
        ACIN[ct] = __builtin_amdgcn_mfma_f32_16x16x32_f16(fWh[ct][kr],      \
                     bfr[kr - 1], ACIN[ct], 0, 0, 0);                       \
    }                                                                       \
    {                                                                       \
      f16x8 h8;                                                             \
      _Pragma("unroll")                                                     \
      for (int ct = 0; ct < 2; ++ct)                                        \
        _Pragma("unroll")                                                   \
        for (int rg = 0; rg < 4; ++rg)                                      \
          h8[ct * 4 + rg] = (f16)fast_tanh(ACIN[ct][rg]);                   \
      *(f16x8*)((char*)&hbuf[(CUR) ^ 1][l15][0] +                           \
                (((w2 * 4 + g + l15) & 31) << 4)) = h8;                     \
      H8K = h8;                                                             \
    }                                                                       \
    _Pragma("unroll")                                                       \
    for (int ct = 0; ct < 2; ++ct) {                                        \
      ACOUT[ct][0] = (float)XWIN[ct][0]; ACOUT[ct][1] = (float)XWIN[ct][1]; \
      ACOUT[ct][2] = (float)XWIN[ct][2]; ACOUT[ct][3] = (float)XWIN[ct][3]; \
    }                                                                       \
    asm volatile("s_waitcnt lgkmcnt(0)\n\ts_barrier" ::: "memory");         \
    __builtin_amdgcn_sched_barrier(0);                                      \
  }

// ================= Fused kernel (96KB dynamic LDS -> 1 WG/CU) =============
__global__ __launch_bounds__(512, 2)
void rnn_fused(const float* __restrict__ x,
               const float* __restrict__ Wx, const float* __restrict__ bx,
               const float* __restrict__ Wh, const float* __restrict__ bh,
               const float* __restrict__ Wp, const float* __restrict__ bp,
               f16* __restrict__ ws, unsigned* __restrict__ flags,
               float* __restrict__ out)
{
  extern __shared__ char smem_raw[];
  const int tid = threadIdx.x;
  const int w2  = tid >> 6;          // wave 0..7
  const int l15 = tid & 15;
  const int g   = (tid >> 4) & 3;

  if (blockIdx.x >= 16) {
    // ---------------- producer role ----------------
    f16 (*xlds)[ND] = (f16 (*)[ND])smem_raw;   // [TCH*R][ND], 32 KB used

    f16x8 fWx[2][4];                 // 32-unit strip per wave
    f32x4 bias2[2];
    #pragma unroll
    for (int ct = 0; ct < 2; ++ct) {
      const int j = w2 * 32 + ct * 16 + l15;
      #pragma unroll
      for (int kt = 0; kt < 4; ++kt)
        fWx[ct][kt] = cvt8(Wx + (size_t)j * ND + kt * 32 + g * 8);
      const int j0 = w2 * 32 + ct * 16 + g * 4;
      #pragma unroll
      for (int rg = 0; rg < 4; ++rg)
        bias2[ct][rg] = bx[j0 + rg] + bh[j0 + rg];
    }

    #pragma unroll 1
    for (int p = blockIdx.x - 16; p < NPAIR; p += NPROD) {
      const int s = p & 15;          // stream
      const int c = p >> 4;          // chunk
      #pragma unroll
      for (int jj = 0; jj < 8; ++jj) {
        const int fi = (tid + jj * 512) * 4;   // flat float idx in chunk
        const int t  = fi >> 11;
        const int rr = (fi >> 7) & 15;
        const int d  = fi & 127;
        f32x4 v = *(const f32x4*)(x + ((size_t)(s * R + rr) * NT
                                     + (size_t)(c * TCH + t)) * ND + d);
        const int m = t * R + rr;
        f16x4 h4;
        h4[0] = (f16)v.x; h4[1] = (f16)v.y; h4[2] = (f16)v.z; h4[3] = (f16)v.w;
        *(f16x4*)((char*)&xlds[m][0] + ((2 * d) ^ ((m & 7) << 4))) = h4;
      }
      __syncthreads();

      #pragma unroll
      for (int t = 0; t < TCH; ++t) {
        f16x8 b[4];
        #pragma unroll
        for (int kt = 0; kt < 4; ++kt) {
          const int m = t * R + l15;
          b[kt] = *(const f16x8*)((char*)&xlds[m][0] +
                   ((kt * 64 + g * 16) ^ ((m & 7) << 4)));
        }
        f16* wsp = ws + ((size_t)(s * NT + c * TCH + t)) * STEP_F16
                      + (w2 * 2) * 256 + g * 64 + l15 * 4;
        #pragma unroll
        for (int ct = 0; ct < 2; ++ct) {
          f32x4 ac = bias2[ct];
          #pragma unroll
          for (int kt = 0; kt < 4; ++kt)
            ac = __builtin_amdgcn_mfma_f32_16x16x32_f16(fWx[ct][kt], b[kt], ac, 0, 0, 0);
          f16x4 pk;
          pk[0] = (f16)ac[0]; pk[1] = (f16)ac[1];
          pk[2] = (f16)ac[2]; pk[3] = (f16)ac[3];
          *(f16x4*)(wsp + ct * 256) = pk;
        }
      }
      __threadfence();
      __syncthreads();
      if (tid == 0)
        __hip_atomic_store(&flags[p], 1u, __ATOMIC_RELEASE,
                           __HIP_MEMORY_SCOPE_AGENT);
    }
    return;
  }

  // ---------------- scan role (round 13 + flag waits) ----------------
  const int wg = blockIdx.x;         // stream id 0..15
  f16 (*hbuf)[R][NH] = (f16 (*)[R][NH])smem_raw;   // [2][16][256], 16 KB

  f16x8 fWh[2][8];                   // wave-rotated, permuted columns
  #pragma unroll
  for (int ct = 0; ct < 2; ++ct) {
    const int j = w2 * 32 + ct * 16 + l15;
    #pragma unroll
    for (int kr = 0; kr < 8; ++kr) {
      const int kta = (w2 + kr) & 7;
      fWh[ct][kr] = cvt44(Wh + (size_t)j * NH + kta * 32 + g * 4,
                          Wh + (size_t)j * NH + kta * 32 + 16 + g * 4);
    }
  }

  {
    unsigned* hz = (unsigned*)&hbuf[0][0][0];
    #pragma unroll
    for (int k = 0; k < (2 * R * NH / 2) / 512; ++k) hz[tid + k * 512] = 0u;
  }

  // wait for chunks 0..4 of this stream
  if (tid < 5) {
    int cc = tid; if (cc > NCH - 1) cc = NCH - 1;
    const int fidx = cc * 16 + wg;
    while (__hip_atomic_load(&flags[fidx], __ATOMIC_ACQUIRE,
                             __HIP_MEMORY_SCOPE_AGENT) == 0u)
      __builtin_amdgcn_s_sleep(8);
  }
  __syncthreads();   // also makes h0 zeros visible

  const f16* wsg = ws + (size_t)wg * NT * STEP_F16
                 + (size_t)(w2 * 2) * 256 + g * 64 + l15 * 4;

  f16x4 xA[2], xB[2];
  #pragma unroll
  for (int ct = 0; ct < 2; ++ct) xA[ct] = *(const f16x4*)(wsg + 0 * STEP_F16 + ct * 256);
  #pragma unroll
  for (int ct = 0; ct < 2; ++ct) xB[ct] = *(const f16x4*)(wsg + 1 * STEP_F16 + ct * 256);

  f32x4 acA[2], acB[2];
  #pragma unroll
  for (int ct = 0; ct < 2; ++ct) {
    acA[ct][0] = (float)xA[ct][0]; acA[ct][1] = (float)xA[ct][1];
    acA[ct][2] = (float)xA[ct][2]; acA[ct][3] = (float)xA[ct][3];
  }

  f16x8 h8k;
  #pragma unroll
  for (int i = 0; i < 8; ++i) h8k[i] = (f16)0.f;

  #pragma unroll 1
  for (int c4 = 0; c4 < NCH; c4 += 4) {
    if (c4 > 0) {
      if (tid < 4) {
        int cc = c4 + 1 + tid; if (cc > NCH - 1) cc = NCH - 1;
        const int fidx = cc * 16 + wg;
        while (__hip_atomic_load(&flags[fidx], __ATOMIC_ACQUIRE,
                                 __HIP_MEMORY_SCOPE_AGENT) == 0u)
          __builtin_amdgcn_s_sleep(8);
      }
      __syncthreads();
    }
    #pragma unroll 1
    for (int tau = c4 * 8; tau < c4 * 8 + 32; tau += 2) {
      DO_STEP(0, acA, acB, xA, xB, h8k, tau);
      DO_STEP(1, acB, acA, xB, xA, h8k, tau + 1);
    }
  }
  // final h is in hbuf[0]

  // ---- output projection: out^T = W_ph . h_T^T + b_ph ----
  f16x8 bh8[8];
  #pragma unroll
  for (int kt = 0; kt < 8; ++kt)
    bh8[kt] = *(const f16x8*)((const char*)&hbuf[0][l15][0] +
              (((kt * 4 + g + l15) & 31) << 4));
  {
    const int j0 = w2 * 16 + g * 4;
    f32x4 ac = {bp[j0], bp[j0 + 1], bp[j0 + 2], bp[j0 + 3]};
    #pragma unroll
    for (int kt = 0; kt < 8; ++kt) {
      const float* wrow = Wp + (size_t)(w2 * 16 + l15) * NH;
      f16x8 afr = cvt44(wrow + kt * 32 + g * 4, wrow + kt * 32 + 16 + g * 4);
      ac = __builtin_amdgcn_mfma_f32_16x16x32_f16(afr, bh8[kt], ac, 0, 0, 0);
    }
    #pragma unroll
    for (int rg = 0; rg < 4; ++rg)
      out[(size_t)(wg * R + l15) * NO + j0 + rg] = ac[rg];
  }
}

// ============ Fallback tier 2: round-13 two-kernel path ============
__global__ __launch_bounds__(256, 2)
void xw_gemm(const float* __restrict__ x,
             const float* __restrict__ Wx, const float* __restrict__ bx,
             const float* __restrict__ bh, f16* __restrict__ ws)
{
  const int wgb = blockIdx.x & 15;
  const int c   = blockIdx.x >> 4;
  const int tid = threadIdx.x;
  const int w   = tid >> 6;
  const int l15 = tid & 15;
  const int g   = (tid >> 4) & 3;

  __shared__ alignas(16) f16 xlds[TCH * R][ND];

  f16x8 fWx[4][4];
  f32x4 bias4[4];
  #pragma unroll
  for (int ct = 0; ct < 4; ++ct) {
    const int j = w * 64 + ct * 16 + l15;
    #pragma unroll
    for (int kt = 0; kt < 4; ++kt)
      fWx[ct][kt] = cvt8(Wx + (size_t)j * ND + kt * 32 + g * 8);
    const int j0 = w * 64 + ct * 16 + g * 4;
    #pragma unroll
    for (int rg = 0; rg < 4; ++rg)
      bias4[ct][rg] = bx[j0 + rg] + bh[j0 + rg];
  }

  const int srow = tid >> 4;
  const int sq   = tid & 15;
  const float* xc = x + ((size_t)(wgb * R + srow) * NT + (size_t)c * TCH) * ND;
  #pragma unroll
  for (int jj = 0; jj < 16; ++jj) {
    const int f = (sq + jj * 16) * 4;
    f32x4 v = *(const f32x4*)(xc + f);
    const int t = f >> 7;
    const int d = f & (ND - 1);
    const int m = t * R + srow;
    f16x4 h4;
    h4[0] = (f16)v.x; h4[1] = (f16)v.y; h4[2] = (f16)v.z; h4[3] = (f16)v.w;
    *(f16x4*)((char*)&xlds[m][0] + ((2 * d) ^ ((m & 7) << 4))) = h4;
  }
  __syncthreads();

  #pragma unroll
  for (int t = 0; t < TCH; ++t) {
    f16x8 b[4];
    #pragma unroll
    for (int kt = 0; kt < 4; ++kt) {
      const int m = t * R + l15;
      b[kt] = *(const f16x8*)((char*)&xlds[m][0] +
               ((kt * 64 + g * 16) ^ ((m & 7) << 4)));
    }
    f16* wsp = ws + ((size_t)(wgb * NT + c * TCH + t)) * STEP_F16
                  + w * 1024 + g * 64 + l15 * 4;
    #pragma unroll
    for (int ct = 0; ct < 4; ++ct) {
      f32x4 ac = bias4[ct];
      #pragma unroll
      for (int kt = 0; kt < 4; ++kt)
        ac = __builtin_amdgcn_mfma_f32_16x16x32_f16(fWx[ct][kt], b[kt], ac, 0, 0, 0);
      f16x4 p;
      p[0] = (f16)ac[0]; p[1] = (f16)ac[1]; p[2] = (f16)ac[2]; p[3] = (f16)ac[3];
      *(f16x4*)(wsp + ct * 256) = p;
    }
  }
}

__global__ __launch_bounds__(512, 2)
void rnn_scan(const f16* __restrict__ ws,
              const float* __restrict__ Wh,
              const float* __restrict__ Wp, const float* __restrict__ bp,
              float* __restrict__ out)
{
  const int wg  = blockIdx.x;
  const int tid = threadIdx.x;
  const int w2  = tid >> 6;
  const int l15 = tid & 15;
  const int g   = (tid >> 4) & 3;

  __shared__ alignas(16) f16 hbuf[2][R][NH];

  f16x8 fWh[2][8];
  #pragma unroll
  for (int ct = 0; ct < 2; ++ct) {
    const int j = w2 * 32 + ct * 16 + l15;
    #pragma unroll
    for (int kr = 0; kr < 8; ++kr) {
      const int kta = (w2 + kr) & 7;
      fWh[ct][kr] = cvt44(Wh + (size_t)j * NH + kta * 32 + g * 4,
                          Wh + (size_t)j * NH + kta * 32 + 16 + g * 4);
    }
  }

  {
    unsigned* hz = (unsigned*)&hbuf[0][0][0];
    #pragma unroll
    for (int k = 0; k < (2 * R * NH / 2) / 512; ++k) hz[tid + k * 512] = 0u;
  }

  const f16* wsg = ws + (size_t)wg * NT * STEP_F16
                 + (size_t)(w2 * 2) * 256 + g * 64 + l15 * 4;

  f16x4 xA[2], xB[2];
  #pragma unroll
  for (int ct = 0; ct < 2; ++ct) xA[ct] = *(const f16x4*)(wsg + 0 * STEP_F16 + ct * 256);
  #pragma unroll
  for (int ct = 0; ct < 2; ++ct) xB[ct] = *(const f16x4*)(wsg + 1 * STEP_F16 + ct * 256);

  f32x4 acA[2], acB[2];
  #pragma unroll
  for (int ct = 0; ct < 2; ++ct) {
    acA[ct][0] = (float)xA[ct][0]; acA[ct][1] = (float)xA[ct][1];
    acA[ct][2] = (float)xA[ct][2]; acA[ct][3] = (float)xA[ct][3];
  }

  f16x8 h8k;
  #pragma unroll
  for (int i = 0; i < 8; ++i) h8k[i] = (f16)0.f;

  __syncthreads();

  #pragma unroll 1
  for (int tau = 0; tau < NT; tau += 2) {
    DO_STEP(0, acA, acB, xA, xB, h8k, tau);
    DO_STEP(1, acB, acA, xB, xA, h8k, tau + 1);
  }

  f16x8 bh8[8];
  #pragma unroll
  for (int kt = 0; kt < 8; ++kt)
    bh8[kt] = *(const f16x8*)((const char*)&hbuf[0][l15][0] +
              (((kt * 4 + g + l15) & 31) << 4));
  {
    const int j0 = w2 * 16 + g * 4;
    f32x4 ac = {bp[j0], bp[j0 + 1], bp[j0 + 2], bp[j0 + 3]};
    #pragma unroll
    for (int kt = 0; kt < 8; ++kt) {
      const float* wrow = Wp + (size_t)(w2 * 16 + l15) * NH;
      f16x8 afr = cvt44(wrow + kt * 32 + g * 4, wrow + kt * 32 + 16 + g * 4);
      ac = __builtin_amdgcn_mfma_f32_16x16x32_f16(afr, bh8[kt], ac, 0, 0, 0);
    }
    #pragma unroll
    for (int rg = 0; rg < 4; ++rg)
      out[(size_t)(wg * R + l15) * NO + j0 + rg] = ac[rg];
  }
}

extern "C" void kernel_launch(void* const* d_in, const int* in_sizes, int n_in,
                              void* d_out, int out_size, void* d_ws, size_t ws_size,
                              hipStream_t stream) {
  const float* x   = (const float*)d_in[0];
  const float* whx = (const float*)d_in[1];
  const float* bhx = (const float*)d_in[2];
  const float* whh = (const float*)d_in[3];
  const float* bhh = (const float*)d_in[4];
  const float* wph = (const float*)d_in[5];
  const float* bph = (const float*)d_in[6];
  float* out = (float*)d_out;
  f16* ws = (f16*)d_ws;

  if (ws_size >= WS_FUSED) {
    unsigned* flags = (unsigned*)((char*)d_ws + WS_XW);
    hipMemsetAsync(flags, 0, 4096, stream);
    rnn_fused<<<dim3(16 + NPROD), dim3(512), DYN_LDS, stream>>>(
        x, whx, bhx, whh, bhh, wph, bph, ws, flags, out);
  } else {
    xw_gemm<<<dim3(16 * NCH), dim3(256), 0, stream>>>(x, whx, bhx, bhh, ws);
    rnn_scan<<<dim3(16), dim3(512), 0, stream>>>(ws, whh, wph, bph, out);
  }
}

// Round 16
// 320.309 us; speedup vs baseline: 1.6240x; 1.6193x over previous
//
#include <hip/hip_runtime.h>

// VanillaRNN for MI355X (gfx950), round 16: revert to round-13 two-kernel
// structure (fusion abandoned: cross-XCD producer->consumer release fences
// cost ~10x the projection itself, rounds 14/15) + padded h rows.
// B=256, T=512, D=128, H=256, O=128, fp32 in/out.
//
// Kernel 1 (xw_gemm, 1024 WGs, (256,2)): xW^T = W_hx . x^T + b -> d_ws, f16,
// scan C-fragment order.
// Kernel 2 (rnn_scan, 16 WGs x 512 thr = 8 waves, 2/SIMD): serial scan.
// Per step: H_new^T = tanh(xW_t^T + W_hh . H^T), mfma_f32_16x16x32_f16.
// h per row = 32 x 16B slots, ROW STRIDE 528B (16B pad: 512B rows are
// 128-dword aligned so same-slot/different-row hits identical banks; 528
// drifts 4 banks/row). Lane (w2,g) owns slot w2*4+g holding units
// w2*32+(i>>2)*16+g*4+(i&3); rotation swizzle slot'=(slot+row)&31; own
// k-tile (kt==w2) kept in VGPRs across the barrier (h8k); fWh wave-rotated
// so all indices compile-time; lgkm-only barrier.
// Fallback single-kernel path if ws_size < 64 MB.

typedef _Float16 f16;
typedef _Float16 f16x2 __attribute__((ext_vector_type(2)));
typedef _Float16 f16x4 __attribute__((ext_vector_type(4)));
typedef _Float16 f16x8 __attribute__((ext_vector_type(8)));
typedef float f32x4 __attribute__((ext_vector_type(4)));

#define NB 256
#define NT 512
#define ND 128
#define NH 256
#define NO 128
#define R  16            // batch rows per stream
#define TCH 8            // timesteps per chunk (xw_gemm)
#define NCH (NT / TCH)   // 64 chunks
#define STEP_F16 4096    // f16 elements per (stream, step) xw block
#define WS_NEED ((size_t)16 * NT * STEP_F16 * 2)   // 67,108,864 bytes
#define ROWB 528                     // padded h row stride (bytes)
#define HHALF (R * ROWB)             // 8448 B per h buffer

__device__ __forceinline__ float fast_tanh(float z) {
  float e = __builtin_amdgcn_exp2f(z * 2.88539008177793f);
  float r = __builtin_amdgcn_rcpf(e + 1.0f);
  return __builtin_fmaf(-2.0f, r, 1.0f);
}

__device__ __forceinline__ f16x8 cvt8(const float* __restrict__ p) {
  f32x4 v0 = *(const f32x4*)p;
  f32x4 v1 = *(const f32x4*)(p + 4);
  f16x8 r;
  r[0] = (f16)v0.x; r[1] = (f16)v0.y; r[2] = (f16)v0.z; r[3] = (f16)v0.w;
  r[4] = (f16)v1.x; r[5] = (f16)v1.y; r[6] = (f16)v1.z; r[7] = (f16)v1.w;
  return r;
}

// fragment from two disjoint f32x4 groups (permuted-column load)
__device__ __forceinline__ f16x8 cvt44(const float* __restrict__ p0,
                                       const float* __restrict__ p1) {
  f32x4 a = *(const f32x4*)p0;
  f32x4 b = *(const f32x4*)p1;
  f16x8 r;
  r[0] = (f16)a.x; r[1] = (f16)a.y; r[2] = (f16)a.z; r[3] = (f16)a.w;
  r[4] = (f16)b.x; r[5] = (f16)b.y; r[6] = (f16)b.z; r[7] = (f16)b.w;
  return r;
}

// ================= Kernel 1: xW^T projection into d_ws ====================
__global__ __launch_bounds__(256, 2)
void xw_gemm(const float* __restrict__ x,
             const float* __restrict__ Wx, const float* __restrict__ bx,
             const float* __restrict__ bh, f16* __restrict__ ws)
{
  const int wgb = blockIdx.x & 15;   // batch-row group (= stream id)
  const int c   = blockIdx.x >> 4;   // chunk
  const int tid = threadIdx.x;
  const int w   = tid >> 6;          // wave: unit strip [w*64, w*64+64)
  const int l15 = tid & 15;
  const int g   = (tid >> 4) & 3;

  __shared__ alignas(16) f16 xlds[TCH * R][ND];   // 32 KB, swizzled (XOR)

  f16x8 fWx[4][4];
  f32x4 bias4[4];
  #pragma unroll
  for (int ct = 0; ct < 4; ++ct) {
    const int j = w * 64 + ct * 16 + l15;
    #pragma unroll
    for (int kt = 0; kt < 4; ++kt)
      fWx[ct][kt] = cvt8(Wx + (size_t)j * ND + kt * 32 + g * 8);
    const int j0 = w * 64 + ct * 16 + g * 4;
    #pragma unroll
    for (int rg = 0; rg < 4; ++rg)
      bias4[ct][rg] = bx[j0 + rg] + bh[j0 + rg];
  }

  const int srow = tid >> 4;
  const int sq   = tid & 15;
  const float* xc = x + ((size_t)(wgb * R + srow) * NT + (size_t)c * TCH) * ND;
  #pragma unroll
  for (int jj = 0; jj < 16; ++jj) {
    const int f = (sq + jj * 16) * 4;
    f32x4 v = *(const f32x4*)(xc + f);
    const int t = f >> 7;
    const int d = f & (ND - 1);
    const int m = t * R + srow;
    f16x4 h4;
    h4[0] = (f16)v.x; h4[1] = (f16)v.y; h4[2] = (f16)v.z; h4[3] = (f16)v.w;
    *(f16x4*)((char*)&xlds[m][0] + ((2 * d) ^ ((m & 7) << 4))) = h4;
  }
  __syncthreads();

  #pragma unroll
  for (int t = 0; t < TCH; ++t) {
    f16x8 b[4];
    #pragma unroll
    for (int kt = 0; kt < 4; ++kt) {
      const int m = t * R + l15;
      b[kt] = *(const f16x8*)((char*)&xlds[m][0] +
               ((kt * 64 + g * 16) ^ ((m & 7) << 4)));
    }
    f16* wsp = ws + ((size_t)(wgb * NT + c * TCH + t)) * STEP_F16
                  + w * 1024 + g * 64 + l15 * 4;
    #pragma unroll
    for (int ct = 0; ct < 4; ++ct) {
      f32x4 ac = bias4[ct];
      #pragma unroll
      for (int kt = 0; kt < 4; ++kt)
        ac = __builtin_amdgcn_mfma_f32_16x16x32_f16(fWx[ct][kt], b[kt], ac, 0, 0, 0);
      f16x4 p;
      p[0] = (f16)ac[0]; p[1] = (f16)ac[1]; p[2] = (f16)ac[2]; p[3] = (f16)ac[3];
      *(f16x4*)(wsp + ct * 256) = p;
    }
  }
}

// ================= Kernel 2: the serial scan (8 waves) ====================
// Own k-tile (kr=0, abs kt=w2) from H8K (registers); kr=1..7 from LDS.
// h rows padded to ROWB=528 B.
#define DO_STEP(CUR, ACIN, ACOUT, XWPF, XWIN, H8K, TAU)                     \
  {                                                                         \
    f16x8 bfr[7];                                                           \
    _Pragma("unroll")                                                       \
    for (int kr = 1; kr < 8; ++kr)                                          \
      bfr[kr - 1] = *(const f16x8*)(hb + (CUR) * HHALF + l15 * ROWB +       \
                ((((w2 + kr) * 4 + g + l15) & 31) << 4));                   \
    int pf = (TAU) + 2; pf = pf < NT ? pf : NT - 1;                         \
    _Pragma("unroll")                                                       \
    for (int ct = 0; ct < 2; ++ct)                                          \
      XWPF[ct] = *(const f16x4*)(wsg + (size_t)pf * STEP_F16 + ct * 256);   \
    _Pragma("unroll")                                                       \
    for (int ct = 0; ct < 2; ++ct)                                          \
      ACIN[ct] = __builtin_amdgcn_mfma_f32_16x16x32_f16(fWh[ct][0], H8K,    \
                   ACIN[ct], 0, 0, 0);                                      \
    _Pragma("unroll")                                                       \
    for (int kr = 1; kr < 8; ++kr) {                                        \
      _Pragma("unroll")                                                     \
      for (int ct = 0; ct < 2; ++ct)                                        \
        ACIN[ct] = __builtin_amdgcn_mfma_f32_16x16x32_f16(fWh[ct][kr],      \
                     bfr[kr - 1], ACIN[ct], 0, 0, 0);                       \
    }                                                                       \
    {                                                                       \
      f16x8 h8;                                                             \
      _Pragma("unroll")                                                     \
      for (int ct = 0; ct < 2; ++ct)                                        \
        _Pragma("unroll")                                                   \
        for (int rg = 0; rg < 4; ++rg)                                      \
          h8[ct * 4 + rg] = (f16)fast_tanh(ACIN[ct][rg]);                   \
      *(f16x8*)(hb + ((CUR) ^ 1) * HHALF + l15 * ROWB +                     \
                (((w2 * 4 + g + l15) & 31) << 4)) = h8;                     \
      H8K = h8;                                                             \
    }                                                                       \
    _Pragma("unroll")                                                       \
    for (int ct = 0; ct < 2; ++ct) {                                        \
      ACOUT[ct][0] = (float)XWIN[ct][0]; ACOUT[ct][1] = (float)XWIN[ct][1]; \
      ACOUT[ct][2] = (float)XWIN[ct][2]; ACOUT[ct][3] = (float)XWIN[ct][3]; \
    }                                                                       \
    asm volatile("s_waitcnt lgkmcnt(0)\n\ts_barrier" ::: "memory");         \
    __builtin_amdgcn_sched_barrier(0);                                      \
  }

__global__ __launch_bounds__(512, 2)
void rnn_scan(const f16* __restrict__ ws,
              const float* __restrict__ Wh,
              const float* __restrict__ Wp, const float* __restrict__ bp,
              float* __restrict__ out)
{
  const int wg  = blockIdx.x;        // stream id 0..15
  const int tid = threadIdx.x;       // 0..511
  const int w2  = tid >> 6;          // wave 0..7: unit strip [w2*32, w2*32+32)
  const int l15 = tid & 15;          // batch row (C col)
  const int g   = (tid >> 4) & 3;

  __shared__ alignas(16) char hb[2 * HHALF];   // 16.5 KB, padded rows, dbuf

  // A-operand: W_hh fragments, WAVE-ROTATED k order: fWh[ct][kr] = absolute
  // k-tile (w2+kr)&7, columns permuted:
  // element i = W_hh[j][kta*32 + (i>>2)*16 + g*4 + (i&3)]
  f16x8 fWh[2][8];
  #pragma unroll
  for (int ct = 0; ct < 2; ++ct) {
    const int j = w2 * 32 + ct * 16 + l15;
    #pragma unroll
    for (int kr = 0; kr < 8; ++kr) {
      const int kta = (w2 + kr) & 7;
      fWh[ct][kr] = cvt44(Wh + (size_t)j * NH + kta * 32 + g * 4,
                          Wh + (size_t)j * NH + kta * 32 + 16 + g * 4);
    }
  }

  for (int k = tid; k < (2 * HHALF) / 4; k += 512)
    ((unsigned*)hb)[k] = 0u;

  // xw base for this lane (C-fragment order)
  const f16* wsg = ws + (size_t)wg * NT * STEP_F16
                 + (size_t)(w2 * 2) * 256 + g * 64 + l15 * 4;

  f16x4 xA[2], xB[2];
  #pragma unroll
  for (int ct = 0; ct < 2; ++ct) xA[ct] = *(const f16x4*)(wsg + 0 * STEP_F16 + ct * 256);
  #pragma unroll
  for (int ct = 0; ct < 2; ++ct) xB[ct] = *(const f16x4*)(wsg + 1 * STEP_F16 + ct * 256);

  f32x4 acA[2], acB[2];
  #pragma unroll
  for (int ct = 0; ct < 2; ++ct) {
    acA[ct][0] = (float)xA[ct][0]; acA[ct][1] = (float)xA[ct][1];
    acA[ct][2] = (float)xA[ct][2]; acA[ct][3] = (float)xA[ct][3];
  }

  f16x8 h8k;   // own-tile B-fragment carried in registers (h0 = 0)
  #pragma unroll
  for (int i = 0; i < 8; ++i) h8k[i] = (f16)0.f;

  __syncthreads();   // h0 zeros visible

  #pragma unroll 1
  for (int tau = 0; tau < NT; tau += 2) {
    DO_STEP(0, acA, acB, xA, xB, h8k, tau);
    DO_STEP(1, acB, acA, xB, xA, h8k, tau + 1);
  }
  // after an even number of steps the final h is in buffer 0

  // ---- output projection: out^T = W_ph . h_T^T + b_ph ----
  f16x8 bh8[8];
  #pragma unroll
  for (int kt = 0; kt < 8; ++kt)
    bh8[kt] = *(const f16x8*)(hb + l15 * ROWB +
              (((kt * 4 + g + l15) & 31) << 4));
  {
    const int j0 = w2 * 16 + g * 4;
    f32x4 ac = {bp[j0], bp[j0 + 1], bp[j0 + 2], bp[j0 + 3]};
    #pragma unroll
    for (int kt = 0; kt < 8; ++kt) {
      const float* wrow = Wp + (size_t)(w2 * 16 + l15) * NH;
      f16x8 afr = cvt44(wrow + kt * 32 + g * 4, wrow + kt * 32 + 16 + g * 4);
      ac = __builtin_amdgcn_mfma_f32_16x16x32_f16(afr, bh8[kt], ac, 0, 0, 0);
    }
    #pragma unroll
    for (int rg = 0; rg < 4; ++rg)
      out[(size_t)(wg * R + l15) * NO + j0 + rg] = ac[rg];
  }
}

// ================= Fallback: round-4 single kernel ====================
__global__ __launch_bounds__(256, 1)
void rnn_mfma(const float* __restrict__ x,
              const float* __restrict__ Wx, const float* __restrict__ bx,
              const float* __restrict__ Wh, const float* __restrict__ bh,
              const float* __restrict__ Wp, const float* __restrict__ bp,
              float* __restrict__ out)
{
  const int wg  = blockIdx.x;
  const int tid = threadIdx.x;
  const int w   = tid >> 6;
  const int l15 = tid & 15;
  const int g   = (tid >> 4) & 3;

  __shared__ alignas(16) f16 xlds[TCH * R][ND];
  __shared__ alignas(16) f16 hbuf[2][R][NH];

  f16x8 fWh[4][8];
  #pragma unroll
  for (int ct = 0; ct < 4; ++ct) {
    const int j = w * 64 + ct * 16 + l15;
    #pragma unroll
    for (int kt = 0; kt < 8; ++kt)
      fWh[ct][kt] = cvt8(Wh + (size_t)j * NH + kt * 32 + g * 8);
  }
  f16x8 fWx[4][4];
  #pragma unroll
  for (int ct = 0; ct < 4; ++ct) {
    const int j = w * 64 + ct * 16 + l15;
    #pragma unroll
    for (int kt = 0; kt < 4; ++kt)
      fWx[ct][kt] = cvt8(Wx + (size_t)j * ND + kt * 32 + g * 8);
  }
  float bias[4];
  #pragma unroll
  for (int ct = 0; ct < 4; ++ct) {
    const int j = w * 64 + ct * 16 + l15;
    bias[ct] = bx[j] + bh[j];
  }
  {
    unsigned* hz = (unsigned*)&hbuf[0][0][0];
    #pragma unroll
    for (int k = 0; k < (R * NH / 2) / 256; ++k) hz[tid + k * 256] = 0u;
  }
  __syncthreads();

  int cur = 0;
  f16x2 xwb[TCH][4][2];
  const int srow = tid >> 4;
  const int sq   = tid & 15;
  const float* xrow = x + (size_t)(wg * R + srow) * NT * ND;

  #pragma unroll 1
  for (int c = 0; c < NCH; ++c) {
    const float* xc = xrow + (size_t)c * TCH * ND;
    #pragma unroll
    for (int jj = 0; jj < 16; ++jj) {
      const int f = (sq + jj * 16) * 4;
      f32x4 v = *(const f32x4*)(xc + f);
      const int t = f >> 7;
      const int d = f & (ND - 1);
      const int m = t * R + srow;
      f16x4 h4;
      h4[0] = (f16)v.x; h4[1] = (f16)v.y; h4[2] = (f16)v.z; h4[3] = (f16)v.w;
      *(f16x4*)((char*)&xlds[m][0] + ((2 * d) ^ ((m & 7) << 4))) = h4;
    }
    __syncthreads();

    #pragma unroll
    for (int t = 0; t < TCH; ++t) {
      f16x8 a[4];
      #pragma unroll
      for (int kt = 0; kt < 4; ++kt) {
        const int m = t * R + l15;
        a[kt] = *(const f16x8*)((char*)&xlds[m][0] +
                 ((kt * 64 + g * 16) ^ ((m & 7) << 4)));
      }
      #pragma unroll
      for (int ct = 0; ct < 4; ++ct) {
        f32x4 ac = {bias[ct], bias[ct], bias[ct], bias[ct]};
        #pragma unroll
        for (int kt = 0; kt < 4; ++kt)
          ac = __builtin_amdgcn_mfma_f32_16x16x32_f16(a[kt], fWx[ct][kt], ac, 0, 0, 0);
        f16x2 p0; p0[0] = (f16)ac[0]; p0[1] = (f16)ac[1];
        f16x2 p1; p1[0] = (f16)ac[2]; p1[1] = (f16)ac[3];
        xwb[t][ct][0] = p0;
        xwb[t][ct][1] = p1;
      }
    }

    #pragma unroll
    for (int s = 0; s < TCH; ++s) {
      f16x8 a[8];
      #pragma unroll
      for (int kt = 0; kt < 8; ++kt) {
        const int m = l15;
        a[kt] = *(const f16x8*)((char*)&hbuf[cur][m][0] +
                 ((kt * 64 + g * 16) ^ ((m & 7) << 4)));
      }
      const int nxt = cur ^ 1;
      #pragma unroll
      for (int ct = 0; ct < 4; ++ct) {
        f32x4 ac  = {(float)xwb[s][ct][0][0], (float)xwb[s][ct][0][1],
                     (float)xwb[s][ct][1][0], (float)xwb[s][ct][1][1]};
        f32x4 ac2 = {0.f, 0.f, 0.f, 0.f};
        #pragma unroll
        for (int kt = 0; kt < 4; ++kt) {
          ac  = __builtin_amdgcn_mfma_f32_16x16x32_f16(a[2*kt],     fWh[ct][2*kt],     ac,  0, 0, 0);
          ac2 = __builtin_amdgcn_mfma_f32_16x16x32_f16(a[2*kt + 1], fWh[ct][2*kt + 1], ac2, 0, 0, 0);
        }
        #pragma unroll
        for (int rg = 0; rg < 4; ++rg) {
          const float th = fast_tanh(ac[rg] + ac2[rg]);
          const int row = g * 4 + rg;
          const int col = w * 64 + ct * 16 + l15;
          *(f16*)((char*)&hbuf[nxt][row][0] +
                  ((2 * col) ^ ((row & 7) << 4))) = (f16)th;
        }
      }
      cur = nxt;
      __syncthreads();
    }
  }

  f16x8 ah[8];
  #pragma unroll
  for (int kt = 0; kt < 8; ++kt) {
    const int m = l15;
    ah[kt] = *(const f16x8*)((char*)&hbuf[cur][m][0] +
             ((kt * 64 + g * 16) ^ ((m & 7) << 4)));
  }
  #pragma unroll
  for (int ct = 0; ct < 2; ++ct) {
    const int o = w * 32 + ct * 16 + l15;
    f32x4 ac = {bp[o], bp[o], bp[o], bp[o]};
    #pragma unroll
    for (int kt = 0; kt < 8; ++kt) {
      f16x8 bfr = cvt8(Wp + (size_t)o * NH + kt * 32 + g * 8);
      ac = __builtin_amdgcn_mfma_f32_16x16x32_f16(ah[kt], bfr, ac, 0, 0, 0);
    }
    #pragma unroll
    for (int rg = 0; rg < 4; ++rg) {
      const int row = g * 4 + rg;
      out[(size_t)(wg * R + row) * NO + o] = ac[rg];
    }
  }
}

extern "C" void kernel_launch(void* const* d_in, const int* in_sizes, int n_in,
                              void* d_out, int out_size, void* d_ws, size_t ws_size,
                              hipStream_t stream) {
  const float* x   = (const float*)d_in[0];
  const float* whx = (const float*)d_in[1];
  const float* bhx = (const float*)d_in[2];
  const float* whh = (const float*)d_in[3];
  const float* bhh = (const float*)d_in[4];
  const float* wph = (const float*)d_in[5];
  const float* bph = (const float*)d_in[6];
  float* out = (float*)d_out;

  if (ws_size >= WS_NEED) {
    f16* ws = (f16*)d_ws;
    xw_gemm<<<dim3(16 * NCH), dim3(256), 0, stream>>>(x, whx, bhx, bhh, ws);
    rnn_scan<<<dim3(16), dim3(512), 0, stream>>>(ws, whh, wph, bph, out);
  } else {
    rnn_mfma<<<dim3(NB / R), dim3(256), 0, stream>>>(x, whx, bhx, whh, bhh, wph, bph, out);
  }
}